// Round 8
// baseline (187.211 us; speedup 1.0000x reference)
//
#include <hip/hip_runtime.h>
#include <hip/hip_bf16.h>

#define B_   64
#define P_   8732
#define C_   81
#define M_   20
#define BP_  (B_*P_)
#define NCH  9            // prior chunks of 1024
#define CER  64           // rows per ce_loc block (256 threads, 4 lanes/row)
#define SBLK 1024

// ---------------- Kernel 1: IoU + threshold truth + per-(gt,chunk) best keys + accum init ----------------
__global__ __launch_bounds__(256) void iou_kernel(
    const float* __restrict__ priors, const float* __restrict__ tboxes,
    int* __restrict__ truth, unsigned long long* __restrict__ bestc,
    int* __restrict__ pos_cnt, float* __restrict__ pos_sum,
    float* __restrict__ accums, int* __restrict__ done)
{
    const int b = blockIdx.y;
    const int tid = threadIdx.x;

    // block (0,0) re-initializes all cross-kernel accumulators every call
    // (ws is 0xAA-poisoned once before timing; every replay must self-init)
    if (blockIdx.x == 0 && b == 0) {
        if (tid < B_) { pos_cnt[tid] = 0; pos_sum[tid] = 0.f; }
        if (tid >= B_ && tid < B_ + 3) accums[tid - B_] = 0.f;
        if (tid == B_ + 3) *done = 0;
    }

    __shared__ float s_gt[M_][4];
    __shared__ float s_ga[M_];
    __shared__ float s_red[M_][4];
    __shared__ int   s_redp[M_][4];

    if (tid < M_*4) ((float*)s_gt)[tid] = tboxes[b*M_*4 + tid];
    __syncthreads();
    if (tid < M_) s_ga[tid] = (s_gt[tid][2]-s_gt[tid][0]) * (s_gt[tid][3]-s_gt[tid][1]);
    __syncthreads();

    float lb[M_]; int lp[M_];
    #pragma unroll
    for (int m=0;m<M_;++m){ lb[m] = -1.0f; lp[m] = 0x7FFFFFFF; }

    const float4* pr4 = (const float4*)priors;
    const int p0 = blockIdx.x * 1024;
    const int pend = min(p0 + 1024, P_);
    for (int p = p0 + tid; p < pend; p += 256) {
        float4 pc = pr4[p];
        float px0 = pc.x - pc.z*0.5f, py0 = pc.y - pc.w*0.5f;
        float px1 = pc.x + pc.z*0.5f, py1 = pc.y + pc.w*0.5f;
        float pa = pc.z * pc.w;
        float best = -1.0f; int bg = 0;
        #pragma unroll
        for (int m=0;m<M_;++m){
            float ix0 = fmaxf(s_gt[m][0], px0);
            float iy0 = fmaxf(s_gt[m][1], py0);
            float ix1 = fminf(s_gt[m][2], px1);
            float iy1 = fminf(s_gt[m][3], py1);
            float iw = fmaxf(ix1-ix0, 0.f), ih = fmaxf(iy1-iy0, 0.f);
            float inter = iw*ih;
            float iou = inter / (s_ga[m] + pa - inter + 1e-10f);
            if (iou > best) { best = iou; bg = m; }       // first-max tie (ascending m)
            if (iou > lb[m]) { lb[m] = iou; lp[m] = p; }  // ascending p: ties keep first
        }
        truth[(size_t)b*P_ + p] = (best >= 0.5f) ? bg : -1;
    }

    const int lane = tid & 63, wid = tid >> 6;
    #pragma unroll
    for (int m=0;m<M_;++m){
        float v = lb[m]; int ip = lp[m];
        for (int off=32; off; off>>=1){
            float ov = __shfl_down(v, off); int op = __shfl_down(ip, off);
            if (ov > v || (ov == v && op < ip)) { v = ov; ip = op; }
        }
        if (lane == 0) { s_red[m][wid] = v; s_redp[m][wid] = ip; }
    }
    __syncthreads();
    if (tid < M_) {
        const int m = tid;
        float v = s_red[m][0]; int ip = s_redp[m][0];
        for (int w=1; w<4; ++w){
            float ov = s_red[m][w]; int op = s_redp[m][w];
            if (ov > v || (ov == v && op < ip)) { v = ov; ip = op; }
        }
        // iou >= 0 always; key: larger iou wins, tie -> smaller p wins
        bestc[(b*M_ + m)*NCH + blockIdx.x] =
            ((unsigned long long)__float_as_uint(v) << 32) | (unsigned)(P_ - 1 - ip);
    }
}

// ---------------- Kernel 2: 4-lane-per-row CE (coalesced, single pass, registers) ----------------
// Lane q of a 4-lane group reads cols {q, q+4, ..., q+80}: per instruction a group's addresses
// are 16 contiguous bytes -> a wave touches ~16 line-segments (vs 64 for lane-per-row).
// Values stay in registers; exp-sum recomputes from regs (no 2nd memory sweep).
__global__ __launch_bounds__(256) void ce_loc_kernel(
    const float* __restrict__ pred_conf, const float* __restrict__ pred_loc,
    const float* __restrict__ priors, const float* __restrict__ tboxes,
    const int* __restrict__ tlabels, const int* __restrict__ truth,
    const unsigned long long* __restrict__ bestc,
    float* __restrict__ ce_neg, int* __restrict__ pos_cnt,
    float* __restrict__ pos_sum, float* __restrict__ accums)
{
    __shared__ int   s_fp[2][M_];      // forced best-prior per spanned batch row
    __shared__ int   s_pos[2];
    __shared__ float s_psum[2];
    __shared__ float s_loc[4];
    const int tid = threadIdx.x;
    const int base = blockIdx.x * CER;
    const int b0 = base / P_;

    // forced-match pairs for the (<=2) batch rows this block spans
    if (tid < 2*M_) {
        const int j = tid / M_, m = tid - j*M_;
        const int bb = b0 + j;
        int p = -1;
        if (bb < B_) {
            const unsigned long long* src = &bestc[(bb*M_ + m)*NCH];
            unsigned long long best = src[0];
            #pragma unroll
            for (int c = 1; c < NCH; ++c) { unsigned long long kk = src[c]; if (kk > best) best = kk; }
            p = P_ - 1 - (int)(unsigned)(best & 0xFFFFFFFFu);
        }
        s_fp[j][m] = p;
    }
    if (tid < 2) { s_pos[tid] = 0; s_psum[tid] = 0.f; }
    __syncthreads();

    const int r = tid >> 2;               // row within block (0..63)
    const int q = tid & 3;                // lane within 4-lane group
    const int bp = base + r;              // grid exact: bp < BP_
    const int b  = bp / P_;
    const int p  = bp - b * P_;
    const int jb = b - b0;
    const float* row = pred_conf + (size_t)bp * C_;

    // single coalesced sweep: 21 interleaved scalar loads into registers
    float v[21];
    #pragma unroll
    for (int i = 0; i < 21; ++i) {
        const int c = q + 4*i;
        v[i] = (c < C_) ? row[c] : -1e30f;   // only q>0,i==20 masked
    }
    float mx = v[0];
    #pragma unroll
    for (int i = 1; i < 21; ++i) mx = fmaxf(mx, v[i]);
    mx = fmaxf(mx, __shfl_xor(mx, 1));
    mx = fmaxf(mx, __shfl_xor(mx, 2));
    float s = 0.f;
    #pragma unroll
    for (int i = 0; i < 21; ++i) s += __expf(v[i] - mx);   // masked -> exp underflows to 0
    s += __shfl_xor(s, 1);
    s += __shfl_xor(s, 2);

    float locacc = 0.f;
    if (q == 0) {
        int t = truth[bp];
        #pragma unroll
        for (int m = 0; m < M_; ++m)      // ascending m: last-wins (numpy scatter)
            if (s_fp[jb][m] == p) t = m;
        const int cls = (t >= 0) ? tlabels[b*M_ + t] : 0;
        const float ce = mx + __logf(s) - row[cls];   // L1-hot re-read; avoids dyn reg index
        if (t >= 0) {
            atomicAdd(&s_pos[jb], 1);
            atomicAdd(&s_psum[jb], ce);
            ce_neg[bp] = 0.f;
            float4 pc = ((const float4*)priors)[p];
            float4 g  = ((const float4*)tboxes)[b*M_ + t];
            float gcx = (g.x+g.z)*0.5f, gcy = (g.y+g.w)*0.5f;
            float gw = g.z - g.x, gh = g.w - g.y;
            float e0 = (gcx - pc.x) / (pc.z * 0.1f);
            float e1 = (gcy - pc.y) / (pc.w * 0.1f);
            float e2 = __logf(gw / pc.z + 1e-5f) * 5.0f;
            float e3 = __logf(gh / pc.w + 1e-5f) * 5.0f;
            float4 pl = ((const float4*)pred_loc)[bp];
            float d0 = pl.x-e0, d1 = pl.y-e1, d2 = pl.z-e2, d3 = pl.w-e3;
            float a0 = fabsf(d0), a1 = fabsf(d1), a2 = fabsf(d2), a3 = fabsf(d3);
            locacc = (a0<1.f ? 0.5f*d0*d0 : a0-0.5f)
                   + (a1<1.f ? 0.5f*d1*d1 : a1-0.5f)
                   + (a2<1.f ? 0.5f*d2*d2 : a2-0.5f)
                   + (a3<1.f ? 0.5f*d3*d3 : a3-0.5f);
        } else {
            ce_neg[bp] = ce;
        }
    }

    for (int off=32; off; off>>=1) locacc += __shfl_down(locacc, off);
    if ((tid & 63) == 0) s_loc[tid>>6] = locacc;
    __syncthreads();
    if (tid == 0) {
        float a = s_loc[0]+s_loc[1]+s_loc[2]+s_loc[3];
        if (a != 0.f) atomicAdd(&accums[0], a);
    }
    if (tid < 2) {
        const int br = b0 + tid;
        if (br < B_ && s_pos[tid] > 0) {
            atomicAdd(&pos_cnt[br], s_pos[tid]);
            atomicAdd(&pos_sum[br], s_psum[tid]);
        }
    }
}

// ---------------- Kernel 3: radix-select top-k (compact candidate list) + finalize ----------------
__global__ __launch_bounds__(SBLK) void select_kernel(
    const float* __restrict__ ce_neg, const int* __restrict__ pos_cnt,
    const float* __restrict__ pos_sum, float* __restrict__ accums,
    int* __restrict__ done, float* __restrict__ out)
{
    const int b = blockIdx.x; const int tid = threadIdx.x;
    const int lane = tid & 63;
    __shared__ float cl[P_];           // compacted MSB-class candidates
    __shared__ unsigned hist[256];
    __shared__ unsigned s_sel, s_prefix, s_remk, s_cntgt;
    __shared__ float s_r1[SBLK/64];
    __shared__ int s_last;

    const float* cerow = ce_neg + (size_t)b * P_;
    if (tid < 256) hist[tid] = 0u;
    if (tid == 0) s_sel = 0u;
    __syncthreads();

    // pass A: MSB-byte histogram, ballot-aggregated (exponent byte is heavily clustered)
    for (int i = tid; i < P_; i += SBLK) {
        const unsigned bin = __float_as_uint(cerow[i]) >> 24;
        unsigned long long todo = __ballot(1);
        while (todo) {
            const int src = (int)__ffsll(todo) - 1;
            const unsigned lead = __shfl(bin, src);
            const unsigned long long mset = __ballot(bin == lead);
            if (lane == src) atomicAdd(&hist[lead], (unsigned)__popcll(mset));
            todo &= ~mset;
        }
    }
    __syncthreads();
    const int pos = pos_cnt[b];
    const unsigned k = (unsigned)min(3 * pos, P_ - 1);
    if (tid == 0) {
        unsigned acc = 0, chosen = 0;
        for (int bin = 255; bin >= 0; --bin) {
            const unsigned c = hist[bin];
            if (acc + c >= k) { chosen = (unsigned)bin; break; }
            acc += c;
        }
        s_prefix = chosen << 24; s_remk = k - acc; s_cntgt = acc;
    }
    __syncthreads();
    const unsigned c3 = s_prefix >> 24;

    // pass B: compact byte-class c3 into cl[]; sum strictly-greater byte classes on the fly
    float gsum = 0.f;
    for (int i = tid; i < P_; i += SBLK) {
        const float v = cerow[i];
        const unsigned byt = __float_as_uint(v) >> 24;
        if (byt > c3) gsum += v;
        const bool pred = (byt == c3);
        const unsigned long long mset = __ballot(pred);
        if (pred) {
            const int leader = (int)__ffsll(mset) - 1;
            unsigned bse;
            if (lane == leader) bse = atomicAdd(&s_sel, (unsigned)__popcll(mset));
            bse = __shfl(bse, leader);
            cl[bse + __popcll(mset & ((1ull << lane) - 1ull))] = v;
        }
    }
    __syncthreads();
    const int L = (int)s_sel;   // >= 1 by choose invariant

    // passes 2..0 over compact list, plain LDS atomics (bins ~uniform -> ~2-way bank alias, free)
    for (int pass = 2; pass >= 0; --pass) {
        if (tid < 256) hist[tid] = 0u;
        __syncthreads();
        const unsigned prefix = s_prefix;
        const int shift = pass * 8;
        const unsigned pmask = 0xFFFFFFFFu << (shift + 8);
        for (int i = tid; i < L; i += SBLK) {
            const unsigned u = __float_as_uint(cl[i]);
            if ((u & pmask) == prefix) atomicAdd(&hist[(u >> shift) & 0xFFu], 1u);
        }
        __syncthreads();
        if (tid == 0) {
            unsigned remk = s_remk, acc = 0, chosen = 0;
            for (int bin = 255; bin >= 0; --bin) {
                const unsigned c = hist[bin];
                if (acc + c >= remk) { chosen = (unsigned)bin; break; }
                acc += c;
            }
            s_cntgt += acc; s_remk = remk - acc; s_prefix = prefix | (chosen << shift);
        }
        __syncthreads();
    }

    const unsigned Tbits = s_prefix;
    const float T = __uint_as_float(Tbits);
    float sgt = gsum;
    for (int i = tid; i < L; i += SBLK) {
        const float v = cl[i];
        if (__float_as_uint(v) > Tbits) sgt += v;   // nonneg floats: bit order == value order
    }
    for (int off=32; off; off>>=1) sgt += __shfl_down(sgt, off);
    if (lane == 0) s_r1[tid>>6] = sgt;
    __syncthreads();
    if (tid == 0) {
        float a = 0.f;
        #pragma unroll
        for (int w = 0; w < SBLK/64; ++w) a += s_r1[w];
        const unsigned sel_eq = s_remk;     // ties at T selected
        float neg_sum, mc;
        if (Tbits != 0u) { neg_sum = a + (float)sel_eq * T; mc = (float)(pos + (int)k); }
        else             { neg_sum = a;                     mc = (float)(pos + (int)s_cntgt); }
        atomicAdd(&accums[1], pos_sum[b] + neg_sum);
        atomicAdd(&accums[2], mc);
        __threadfence();
        const int old = atomicAdd(done, 1);
        s_last = (old == B_ - 1);
    }
    __syncthreads();
    if (tid == 0 && s_last) {
        const float l  = atomicAdd(&accums[0], 0.f);
        const float cs = atomicAdd(&accums[1], 0.f);
        const float mn = atomicAdd(&accums[2], 0.f);
        out[0] = l / (float)B_;
        out[1] = cs / mn / (float)B_;
    }
}

extern "C" void kernel_launch(void* const* d_in, const int* in_sizes, int n_in,
                              void* d_out, int out_size, void* d_ws, size_t ws_size,
                              hipStream_t stream) {
    (void)in_sizes; (void)n_in; (void)out_size; (void)ws_size;
    const float* pred_loc  = (const float*)d_in[0];
    const float* pred_conf = (const float*)d_in[1];
    const float* priors    = (const float*)d_in[2];
    const float* tboxes    = (const float*)d_in[3];
    const int*   tlabels   = (const int*)d_in[4];
    float* out = (float*)d_out;

    char* ws = (char*)d_ws;
    int*   truth  = (int*)ws;                                 // BP ints
    float* ce_neg = (float*)(ws + (size_t)BP_ * 4);           // BP floats
    unsigned long long* bestc = (unsigned long long*)(ws + (size_t)BP_ * 8);  // B*M*9 u64
    char* tail = ws + (size_t)BP_ * 8 + (size_t)B_*M_*NCH*8;
    int*   pos_cnt = (int*)tail;                              // B ints
    float* pos_sum = (float*)(tail + B_*4);                   // B floats
    float* accums  = (float*)(tail + B_*8);                   // [loc, conf, maskcnt]
    int*   done    = (int*)(tail + B_*8 + 12);

    iou_kernel<<<dim3(NCH, B_), 256, 0, stream>>>(priors, tboxes, truth, bestc,
                                                  pos_cnt, pos_sum, accums, done);
    ce_loc_kernel<<<BP_ / CER, 256, 0, stream>>>(pred_conf, pred_loc, priors, tboxes,
                                                 tlabels, truth, bestc,
                                                 ce_neg, pos_cnt, pos_sum, accums);
    select_kernel<<<B_, SBLK, 0, stream>>>(ce_neg, pos_cnt, pos_sum, accums, done, out);
}

// Round 9
// 154.775 us; speedup vs baseline: 1.2096x; 1.2096x over previous
//
#include <hip/hip_runtime.h>
#include <hip/hip_bf16.h>

#define B_   64
#define P_   8732
#define C_   81
#define M_   20
#define BP_  (B_*P_)
#define CEB  128
#define CETH 512
#define NV   (CEB*C_/4)   // 2592 float4 per block
#define NCH  9            // prior chunks of 1024
#define SBLK 1024

// ---------------- Kernel 1: IoU + threshold truth + per-(gt,chunk) best keys + accum init ----------------
__global__ __launch_bounds__(256) void iou_kernel(
    const float* __restrict__ priors, const float* __restrict__ tboxes,
    int* __restrict__ truth, unsigned long long* __restrict__ bestc,
    int* __restrict__ pos_cnt, float* __restrict__ pos_sum,
    float* __restrict__ accums, int* __restrict__ done)
{
    const int b = blockIdx.y;
    const int tid = threadIdx.x;

    // block (0,0) re-initializes all cross-kernel accumulators every call
    // (ws is 0xAA-poisoned once before timing; every replay must self-init)
    if (blockIdx.x == 0 && b == 0) {
        if (tid < B_) { pos_cnt[tid] = 0; pos_sum[tid] = 0.f; }
        if (tid >= B_ && tid < B_ + 3) accums[tid - B_] = 0.f;
        if (tid == B_ + 3) *done = 0;
    }

    __shared__ float s_gt[M_][4];
    __shared__ float s_ga[M_];
    __shared__ float s_red[M_][4];
    __shared__ int   s_redp[M_][4];

    if (tid < M_*4) ((float*)s_gt)[tid] = tboxes[b*M_*4 + tid];
    __syncthreads();
    if (tid < M_) s_ga[tid] = (s_gt[tid][2]-s_gt[tid][0]) * (s_gt[tid][3]-s_gt[tid][1]);
    __syncthreads();

    float lb[M_]; int lp[M_];
    #pragma unroll
    for (int m=0;m<M_;++m){ lb[m] = -1.0f; lp[m] = 0x7FFFFFFF; }

    const float4* pr4 = (const float4*)priors;
    const int p0 = blockIdx.x * 1024;
    const int pend = min(p0 + 1024, P_);
    for (int p = p0 + tid; p < pend; p += 256) {
        float4 pc = pr4[p];
        float px0 = pc.x - pc.z*0.5f, py0 = pc.y - pc.w*0.5f;
        float px1 = pc.x + pc.z*0.5f, py1 = pc.y + pc.w*0.5f;
        float pa = pc.z * pc.w;
        float best = -1.0f; int bg = 0;
        #pragma unroll
        for (int m=0;m<M_;++m){
            float ix0 = fmaxf(s_gt[m][0], px0);
            float iy0 = fmaxf(s_gt[m][1], py0);
            float ix1 = fminf(s_gt[m][2], px1);
            float iy1 = fminf(s_gt[m][3], py1);
            float iw = fmaxf(ix1-ix0, 0.f), ih = fmaxf(iy1-iy0, 0.f);
            float inter = iw*ih;
            float iou = inter / (s_ga[m] + pa - inter + 1e-10f);
            if (iou > best) { best = iou; bg = m; }       // first-max tie (ascending m)
            if (iou > lb[m]) { lb[m] = iou; lp[m] = p; }  // ascending p: ties keep first
        }
        truth[(size_t)b*P_ + p] = (best >= 0.5f) ? bg : -1;
    }

    const int lane = tid & 63, wid = tid >> 6;
    #pragma unroll
    for (int m=0;m<M_;++m){
        float v = lb[m]; int ip = lp[m];
        for (int off=32; off; off>>=1){
            float ov = __shfl_down(v, off); int op = __shfl_down(ip, off);
            if (ov > v || (ov == v && op < ip)) { v = ov; ip = op; }
        }
        if (lane == 0) { s_red[m][wid] = v; s_redp[m][wid] = ip; }
    }
    __syncthreads();
    if (tid < M_) {
        const int m = tid;
        float v = s_red[m][0]; int ip = s_redp[m][0];
        for (int w=1; w<4; ++w){
            float ov = s_red[m][w]; int op = s_redp[m][w];
            if (ov > v || (ov == v && op < ip)) { v = ov; ip = op; }
        }
        // iou >= 0 always; key: larger iou wins, tie -> smaller p wins
        bestc[(b*M_ + m)*NCH + blockIdx.x] =
            ((unsigned long long)__float_as_uint(v) << 32) | (unsigned)(P_ - 1 - ip);
    }
}

// ---------------- Kernel 2: fused CE + local forced-match override + smooth-L1 + pos stats ----------------
// R5-proven structure: async global_load_lds staging, CEB=128, 512 threads (4 lanes/row),
// NO min-waves clamp (R6's (256,7) clamp -> 36 VGPR was the regression).
__global__ __launch_bounds__(CETH) void ce_loc_kernel(
    const float* __restrict__ pred_conf, const float* __restrict__ pred_loc,
    const float* __restrict__ priors, const float* __restrict__ tboxes,
    const int* __restrict__ tlabels, const int* __restrict__ truth,
    const unsigned long long* __restrict__ bestc,
    float* __restrict__ ce_neg, int* __restrict__ pos_cnt,
    float* __restrict__ pos_sum, float* __restrict__ accums)
{
    __shared__ float sc[CEB * C_];     // 41.5 KB -> 3 blocks/CU, 24 waves
    __shared__ int   s_fp[2][M_];      // forced best-prior per spanned batch row
    __shared__ int   s_pos[2];
    __shared__ float s_psum[2];
    __shared__ float s_loc[CETH/64];
    const int tid = threadIdx.x;
    const int base = blockIdx.x * CEB;
    const int b0 = base / P_;

    const float4* src4 = (const float4*)(pred_conf + (size_t)base * C_);
    float4* dst4 = (float4*)sc;
#if __has_builtin(__builtin_amdgcn_global_load_lds)
    // async fire-and-forget staging: no VGPR roundtrip; barrier drains vmcnt
    #pragma unroll
    for (int k = 0; k < NV / CETH; ++k) {   // 5 * 512 = 2560
        const int i = tid + k * CETH;
        __builtin_amdgcn_global_load_lds(
            (const __attribute__((address_space(1))) void*)(src4 + i),
            (__attribute__((address_space(3))) void*)(dst4 + i), 16, 0, 0);
    }
    if (tid < NV - (NV / CETH) * CETH) {    // tail: 32 lanes
        const int i = (NV / CETH) * CETH + tid;
        __builtin_amdgcn_global_load_lds(
            (const __attribute__((address_space(1))) void*)(src4 + i),
            (__attribute__((address_space(3))) void*)(dst4 + i), 16, 0, 0);
    }
#else
    for (int i = tid; i < NV; i += CETH) dst4[i] = src4[i];
#endif

    // forced-match pairs for the (<=2) batch rows this block spans
    if (tid < 2*M_) {
        const int j = tid / M_, m = tid - j*M_;
        const int bb = b0 + j;
        int p = -1;
        if (bb < B_) {
            const unsigned long long* src = &bestc[(bb*M_ + m)*NCH];
            unsigned long long best = src[0];
            #pragma unroll
            for (int c = 1; c < NCH; ++c) { unsigned long long kk = src[c]; if (kk > best) best = kk; }
            p = P_ - 1 - (int)(unsigned)(best & 0xFFFFFFFFu);
        }
        s_fp[j][m] = p;
    }
    if (tid < 2) { s_pos[tid] = 0; s_psum[tid] = 0.f; }
    __syncthreads();

    // 4 lanes per row: q=0 -> cols [0,21), q>0 -> [q*20+1, q*20+21)
    const int r = tid >> 2;
    const int q = tid & 3;
    const float* row = &sc[r * C_];
    const int c0 = q * 20 + (q > 0 ? 1 : 0);
    const int cn = (q == 0) ? 21 : 20;
    float mx = -1e30f;
    for (int c = 0; c < cn; ++c) mx = fmaxf(mx, row[c0 + c]);
    mx = fmaxf(mx, __shfl_xor(mx, 1));
    mx = fmaxf(mx, __shfl_xor(mx, 2));
    float s = 0.f;
    for (int c = 0; c < cn; ++c) s += __expf(row[c0 + c] - mx);
    s += __shfl_xor(s, 1);
    s += __shfl_xor(s, 2);

    float locacc = 0.f;
    if (q == 0) {
        const int bp = base + r;
        const int b = bp / P_;
        const int p = bp - b * P_;
        const int jb = b - b0;
        int t = truth[bp];
        #pragma unroll
        for (int m = 0; m < M_; ++m)      // ascending m: last-wins (numpy scatter)
            if (s_fp[jb][m] == p) t = m;
        const int cls = (t >= 0) ? tlabels[b*M_ + t] : 0;
        const float ce = mx + __logf(s) - row[cls];
        if (t >= 0) {
            atomicAdd(&s_pos[jb], 1);
            atomicAdd(&s_psum[jb], ce);
            ce_neg[bp] = 0.f;
            float4 pc = ((const float4*)priors)[p];
            float4 g  = ((const float4*)tboxes)[b*M_ + t];
            float gcx = (g.x+g.z)*0.5f, gcy = (g.y+g.w)*0.5f;
            float gw = g.z - g.x, gh = g.w - g.y;
            float e0 = (gcx - pc.x) / (pc.z * 0.1f);
            float e1 = (gcy - pc.y) / (pc.w * 0.1f);
            float e2 = __logf(gw / pc.z + 1e-5f) * 5.0f;
            float e3 = __logf(gh / pc.w + 1e-5f) * 5.0f;
            float4 pl = ((const float4*)pred_loc)[bp];
            float d0 = pl.x-e0, d1 = pl.y-e1, d2 = pl.z-e2, d3 = pl.w-e3;
            float a0 = fabsf(d0), a1 = fabsf(d1), a2 = fabsf(d2), a3 = fabsf(d3);
            locacc = (a0<1.f ? 0.5f*d0*d0 : a0-0.5f)
                   + (a1<1.f ? 0.5f*d1*d1 : a1-0.5f)
                   + (a2<1.f ? 0.5f*d2*d2 : a2-0.5f)
                   + (a3<1.f ? 0.5f*d3*d3 : a3-0.5f);
        } else {
            ce_neg[bp] = ce;
        }
    }
    for (int off=32; off; off>>=1) locacc += __shfl_down(locacc, off);
    if ((tid & 63) == 0) s_loc[tid>>6] = locacc;
    __syncthreads();
    if (tid == 0) {
        float a = 0.f;
        #pragma unroll
        for (int w = 0; w < CETH/64; ++w) a += s_loc[w];
        if (a != 0.f) atomicAdd(&accums[0], a);
    }
    if (tid < 2) {
        const int br = b0 + tid;
        if (br < B_ && s_pos[tid] > 0) {
            atomicAdd(&pos_cnt[br], s_pos[tid]);
            atomicAdd(&pos_sum[br], s_psum[tid]);
        }
    }
}

// ---------------- Kernel 3: radix-select top-k (compact candidate list) + finalize ----------------
__global__ __launch_bounds__(SBLK) void select_kernel(
    const float* __restrict__ ce_neg, const int* __restrict__ pos_cnt,
    const float* __restrict__ pos_sum, float* __restrict__ accums,
    int* __restrict__ done, float* __restrict__ out)
{
    const int b = blockIdx.x; const int tid = threadIdx.x;
    const int lane = tid & 63;
    __shared__ float cl[P_];           // compacted MSB-class candidates
    __shared__ unsigned hist[256];
    __shared__ unsigned s_sel, s_prefix, s_remk, s_cntgt;
    __shared__ float s_r1[SBLK/64];
    __shared__ int s_last;

    const float* cerow = ce_neg + (size_t)b * P_;
    if (tid < 256) hist[tid] = 0u;
    if (tid == 0) s_sel = 0u;
    __syncthreads();

    // pass A: MSB-byte histogram, ballot-aggregated (exponent byte is heavily clustered)
    for (int i = tid; i < P_; i += SBLK) {
        const unsigned bin = __float_as_uint(cerow[i]) >> 24;
        unsigned long long todo = __ballot(1);
        while (todo) {
            const int src = (int)__ffsll(todo) - 1;
            const unsigned lead = __shfl(bin, src);
            const unsigned long long mset = __ballot(bin == lead);
            if (lane == src) atomicAdd(&hist[lead], (unsigned)__popcll(mset));
            todo &= ~mset;
        }
    }
    __syncthreads();
    const int pos = pos_cnt[b];
    const unsigned k = (unsigned)min(3 * pos, P_ - 1);
    if (tid == 0) {
        unsigned acc = 0, chosen = 0;
        for (int bin = 255; bin >= 0; --bin) {
            const unsigned c = hist[bin];
            if (acc + c >= k) { chosen = (unsigned)bin; break; }
            acc += c;
        }
        s_prefix = chosen << 24; s_remk = k - acc; s_cntgt = acc;
    }
    __syncthreads();
    const unsigned c3 = s_prefix >> 24;

    // pass B: compact byte-class c3 into cl[]; sum strictly-greater byte classes on the fly
    float gsum = 0.f;
    for (int i = tid; i < P_; i += SBLK) {
        const float v = cerow[i];
        const unsigned byt = __float_as_uint(v) >> 24;
        if (byt > c3) gsum += v;
        const bool pred = (byt == c3);
        const unsigned long long mset = __ballot(pred);
        if (pred) {
            const int leader = (int)__ffsll(mset) - 1;
            unsigned bse;
            if (lane == leader) bse = atomicAdd(&s_sel, (unsigned)__popcll(mset));
            bse = __shfl(bse, leader);
            cl[bse + __popcll(mset & ((1ull << lane) - 1ull))] = v;
        }
    }
    __syncthreads();
    const int L = (int)s_sel;   // >= 1 by choose invariant

    // passes 2..0 over compact list, plain LDS atomics (bins ~uniform -> ~2-way bank alias, free)
    for (int pass = 2; pass >= 0; --pass) {
        if (tid < 256) hist[tid] = 0u;
        __syncthreads();
        const unsigned prefix = s_prefix;
        const int shift = pass * 8;
        const unsigned pmask = 0xFFFFFFFFu << (shift + 8);
        for (int i = tid; i < L; i += SBLK) {
            const unsigned u = __float_as_uint(cl[i]);
            if ((u & pmask) == prefix) atomicAdd(&hist[(u >> shift) & 0xFFu], 1u);
        }
        __syncthreads();
        if (tid == 0) {
            unsigned remk = s_remk, acc = 0, chosen = 0;
            for (int bin = 255; bin >= 0; --bin) {
                const unsigned c = hist[bin];
                if (acc + c >= remk) { chosen = (unsigned)bin; break; }
                acc += c;
            }
            s_cntgt += acc; s_remk = remk - acc; s_prefix = prefix | (chosen << shift);
        }
        __syncthreads();
    }

    const unsigned Tbits = s_prefix;
    const float T = __uint_as_float(Tbits);
    float sgt = gsum;
    for (int i = tid; i < L; i += SBLK) {
        const float v = cl[i];
        if (__float_as_uint(v) > Tbits) sgt += v;   // nonneg floats: bit order == value order
    }
    for (int off=32; off; off>>=1) sgt += __shfl_down(sgt, off);
    if (lane == 0) s_r1[tid>>6] = sgt;
    __syncthreads();
    if (tid == 0) {
        float a = 0.f;
        #pragma unroll
        for (int w = 0; w < SBLK/64; ++w) a += s_r1[w];
        const unsigned sel_eq = s_remk;     // ties at T selected
        float neg_sum, mc;
        if (Tbits != 0u) { neg_sum = a + (float)sel_eq * T; mc = (float)(pos + (int)k); }
        else             { neg_sum = a;                     mc = (float)(pos + (int)s_cntgt); }
        atomicAdd(&accums[1], pos_sum[b] + neg_sum);
        atomicAdd(&accums[2], mc);
        __threadfence();
        const int old = atomicAdd(done, 1);
        s_last = (old == B_ - 1);
    }
    __syncthreads();
    if (tid == 0 && s_last) {
        const float l  = atomicAdd(&accums[0], 0.f);
        const float cs = atomicAdd(&accums[1], 0.f);
        const float mn = atomicAdd(&accums[2], 0.f);
        out[0] = l / (float)B_;
        out[1] = cs / mn / (float)B_;
    }
}

extern "C" void kernel_launch(void* const* d_in, const int* in_sizes, int n_in,
                              void* d_out, int out_size, void* d_ws, size_t ws_size,
                              hipStream_t stream) {
    (void)in_sizes; (void)n_in; (void)out_size; (void)ws_size;
    const float* pred_loc  = (const float*)d_in[0];
    const float* pred_conf = (const float*)d_in[1];
    const float* priors    = (const float*)d_in[2];
    const float* tboxes    = (const float*)d_in[3];
    const int*   tlabels   = (const int*)d_in[4];
    float* out = (float*)d_out;

    char* ws = (char*)d_ws;
    int*   truth  = (int*)ws;                                 // BP ints
    float* ce_neg = (float*)(ws + (size_t)BP_ * 4);           // BP floats
    unsigned long long* bestc = (unsigned long long*)(ws + (size_t)BP_ * 8);  // B*M*9 u64
    char* tail = ws + (size_t)BP_ * 8 + (size_t)B_*M_*NCH*8;
    int*   pos_cnt = (int*)tail;                              // B ints
    float* pos_sum = (float*)(tail + B_*4);                   // B floats
    float* accums  = (float*)(tail + B_*8);                   // [loc, conf, maskcnt]
    int*   done    = (int*)(tail + B_*8 + 12);

    iou_kernel<<<dim3(NCH, B_), 256, 0, stream>>>(priors, tboxes, truth, bestc,
                                                  pos_cnt, pos_sum, accums, done);
    ce_loc_kernel<<<BP_ / CEB, CETH, 0, stream>>>(pred_conf, pred_loc, priors, tboxes,
                                                  tlabels, truth, bestc,
                                                  ce_neg, pos_cnt, pos_sum, accums);
    select_kernel<<<B_, SBLK, 0, stream>>>(ce_neg, pos_cnt, pos_sum, accums, done, out);
}